// Round 10
// baseline (125.260 us; speedup 1.0000x reference)
//
#include <hip/hip_runtime.h>
#include <math.h>

#define BLOCK 256
#define SPB (BLOCK / 4)   // 64 samples per block; 4 lanes cooperate per sample
// Session rules: (R4) no runtime-indexed register arrays; (R5) no fine-grained
// scalar guards around register-resident straight-line code; (R7) dynamic chunk
// loops with wave-uniform scalar bounds + LDS t-table is the winning shape;
// (R8) even-rounded pairing re-added evals -> neutral; (R9) exact-count pairing
// + i=1 shift -> issue-lean but latency-bound (VALUBusy 35%). R10: hide LDS
// latency -- hoist the (shared) first pair, software-prefetch the next pair
// inside each loop. FLOP sequence bit-identical to R9.

struct F4a4 { float a, b, c, d; };   // 16B load at 4B alignment -> global_load_dwordx4

__device__ __forceinline__ float exp2_fast(float x) {
#if __has_builtin(__builtin_amdgcn_exp2f)
    return __builtin_amdgcn_exp2f(x);   // bare v_exp_f32
#else
    return __expf(x * 0.69314718055994531f);
#endif
}

// Inline f64 exp, rel err ~7e-15. Proven R5-R9 (absmax identical to libm).
__device__ __forceinline__ double exp_f64_fast(double x) {
    const double L2E = 1.4426950408889634074;
    const double LN2 = 0.69314718055994530942;
    double n = rint(x * L2E);
    double r = fma(x, L2E, -n);
    double w = r * LN2;
    double p = 2.08767569878680989792e-9;             // 1/12!
    p = fma(p, w, 2.50521083854417187751e-8);
    p = fma(p, w, 2.75573192239858906526e-7);
    p = fma(p, w, 2.75573192239858925110e-6);
    p = fma(p, w, 2.48015873015873015873e-5);
    p = fma(p, w, 1.98412698412698412698e-4);
    p = fma(p, w, 1.38888888888888888889e-3);
    p = fma(p, w, 8.33333333333333333333e-3);
    p = fma(p, w, 4.16666666666666666667e-2);
    p = fma(p, w, 1.66666666666666666667e-1);
    p = fma(p, w, 0.5);
    p = fma(p, w, 1.0);
    p = fma(p, w, 1.0);
    const double sc = __longlong_as_double((long long)(1023 + (int)n) << 52);
    return p * sc;
}

__global__ __launch_bounds__(BLOCK) void lbd_kernel(
    const int* __restrict__ uid_in, const int* __restrict__ iid_in,
    const float* __restrict__ uf,  const float* __restrict__ vf,
    const float* __restrict__ ubt, const float* __restrict__ ibt,
    const float* __restrict__ uae, const float* __restrict__ ube,
    const float* __restrict__ iae, const float* __restrict__ ibe,
    const float* __restrict__ gbp, float* __restrict__ out, int B)
{
    // Sample-independent t-grid tables: built once per block.
    // s_num padded to 72: prefetch reads up to i = 64+sub+1 <= 68; pad entries
    // are (t=1, lt=0) -> finite math, masked to exact 0 if ever consumed.
    __shared__ float2 s_num[72];   // (t_i, log2 t_i); [63..71] -> (1, 0)
    __shared__ float2 s_den[64];   // (log2 t_i, log2(1-t_i))
    const int tid = threadIdx.x;
    if (tid < 72) {
        const double STEP0 = 1.0 / 63.0;
        float tf = (tid >= 63) ? 1.0f : (float)((double)tid * STEP0); // exact np linspace f32
        const float lt = __log2f(tf);                 // tid>=63 -> 0
        s_num[tid] = make_float2(tf, lt);
        if (tid < 64) s_den[tid] = make_float2(lt, __log2f(1.0f - tf));
    }
    __syncthreads();

    const int sub = tid & 3;                          // lane within 4-lane sample group
    const int s0  = blockIdx.x * SPB + (tid >> 2);
    const bool valid = (s0 < B);
    const int s = valid ? s0 : (B - 1);               // clamp: keep lanes live for shuffles

    const int u = uid_in[s];
    const int v = iid_in[s];

    // ---- feature gather: 4 x dwordx4 per table; lane covers 16c+4*sub..+3 -----
    const float* pu = uf + (long long)u * 65;
    const float* pv = vf + (long long)v * 65;
    float dotp = 0.f, sup = 0.f, svp = 0.f;
#pragma unroll
    for (int c = 0; c < 4; ++c) {
        const F4a4 a = *(const F4a4*)(pu + c * 16 + sub * 4);
        const F4a4 b = *(const F4a4*)(pv + c * 16 + sub * 4);
        dotp += a.a * b.a + a.b * b.b + a.c * b.c + a.d * b.d;
        sup  += a.a * a.a + a.b * a.b + a.c * a.c + a.d * a.d;
        svp  += b.a * b.a + b.b * b.b + b.c * b.c + b.d * b.d;
    }
#pragma unroll
    for (int d = 1; d < 4; d <<= 1) {                 // butterfly within 4-group
        dotp += __shfl_xor(dotp, d, 64);
        sup  += __shfl_xor(sup,  d, 64);
        svp  += __shfl_xor(svp,  d, 64);
    }

    // ---- embedding gather dedup: 1 load/lane + shuffles (smooth path) ---------
    float emb;
    {
        const float* ep = (sub == 0) ? (uae + u)
                        : (sub == 1) ? (iae + v)
                        : (sub == 2) ? (ube + u)
                        :              (ibe + v);
        emb = *ep;
    }
    const float ua_ = __shfl(emb, 0, 4);
    const float ia_ = __shfl(emb, 1, 4);
    const float ub_ = __shfl(emb, 2, 4);
    const float ib_ = __shfl(emb, 3, 4);

    // ---- alpha / beta (smooth; 4 lanes redundantly) ---------------------------
    const float gb = gbp[0];
    const float len_prod = sqrtf(sup) * sqrtf(svp);
    const float EPS = 1e-6f;
    const float HI  = (float)(1.0 - 1e-6);
    float mu = 0.5f + (0.5f * dotp) / fmaxf(len_prod, EPS);
    mu = fminf(fmaxf(mu, EPS), HI);
    const float ups = fmaxf(fabsf(dotp), EPS);
    const float al0 = fmaxf(0.01f, mu * ups);
    const float be0 = fmaxf(0.01f, ups - al0);
    const float alpha = fmaxf(0.01f, ((gb + al0) + ua_) + ia_);
    const float beta  = fmaxf(0.01f, ((gb + be0) + ub_) + ib_);
    const float am1 = alpha - 1.0f;                   // > 0 (gb = 2.0)
    const float bm1 = beta  - 1.0f;                   // > 0

    // ---- bin-edge chain in f64 (mask-critical; slop budget ~1e-11 rel) --------
    // Lane sub owns contiguous bins lb..lb+2 (lane3: bin 9 only).
    const double STEP = 1.0 / 63.0;
    const int lb = 3 * sub;
    double e0, e1 = 0.0, e2 = 0.0;
    {
        const long long ur = (long long)u * 10, vr = (long long)v * 10;
        const int i1 = (lb + 1 <= 9) ? lb + 1 : 9;    // clamp to stay in-bounds
        const int i2 = (lb + 2 <= 9) ? lb + 2 : 9;
        e0 = exp_f64_fast((double)ubt[ur + lb] + (double)ibt[vr + lb]);
        const double t1 = exp_f64_fast((double)ubt[ur + i1] + (double)ibt[vr + i1]);
        const double t2 = exp_f64_fast((double)ubt[ur + i2] + (double)ibt[vr + i2]);
        if (lb + 1 <= 9) e1 = t1;                     // lane3 contributes only bin 9
        if (lb + 2 <= 9) e2 = t2;
    }
    const double c0 = e0, c1 = c0 + e1, c2 = c1 + e2; // local cumsum (3 bins)
    double p = c2;                                    // local total
#pragma unroll
    for (int d = 1; d < 4; d <<= 1) {                 // inclusive scan of totals
        const double t = __shfl_up(p, d, 4);
        if (sub >= d) p += t;
    }
    const double ssum = __shfl(p, 3, 4);              // grand total (10 bins)
    const double rsum = 1.0 / ssum;                   // 1 IEEE div; <=2ulp slop ok
    const double ex   = p - c2;                       // exclusive prefix
    // own edges at static slots r=0..2 (global edge index lb+r, valid if <= 8)
    float xf_own[3] = {0.f, 0.f, 0.f}, lx_own[3] = {0.f, 0.f, 0.f};
    int   im_own[3] = {0, 0, 0};
    const double cg0 = ex + c0, cg1 = ex + c1, cg2 = ex + c2;
#pragma unroll
    for (int r = 0; r < 3; ++r) {
        const double cgr = (r == 0) ? cg0 : (r == 1) ? cg1 : cg2;
        if (lb + r <= 8) {
            const double x = cgr * rsum;              // f64 mul by reciprocal
            int k = (int)(x * 63.0);
            k = (k > 62) ? 62 : k;
            const int dec = ((double)k * STEP > x) ? 1 : 0;
            const int inc = ((k < 62) && ((double)(k + 1) * STEP <= x)) ? 1 : 0;
            im_own[r] = k + inc - dec;                // exact im, branch-free
            xf_own[r] = (float)x;
            lx_own[r] = __log2f(xf_own[r]);
        }
    }

    // ---- broadcast edges to the 4-group; wave-uniform scalar chunk bounds -----
    // With the i = 4m+sub+1 shift, trips = ceil(im/4) (exact; no dead i=0 eval).
    float xfj[9], alxj[9];
    int   imj[9], Mw[9];
#pragma unroll
    for (int j = 0; j < 9; ++j) {
        const int src  = j / 3;                       // compile-time
        const int slot = j % 3;                       // compile-time
        const float xo = (slot == 0) ? xf_own[0] : (slot == 1) ? xf_own[1] : xf_own[2];
        const float lo = (slot == 0) ? lx_own[0] : (slot == 1) ? lx_own[1] : lx_own[2];
        const int   io = (slot == 0) ? im_own[0] : (slot == 1) ? im_own[1] : im_own[2];
        xfj[j]  = __shfl(xo, src, 4);
        alxj[j] = am1 * __shfl(lo, src, 4);
        imj[j]  = __shfl(io, src, 4);
        int mm = imj[j];
        mm = max(mm, __shfl_xor(mm, 4, 64));          // max over the wave's 16 groups
        mm = max(mm, __shfl_xor(mm, 8, 64));
        mm = max(mm, __shfl_xor(mm, 16, 64));
        mm = max(mm, __shfl_xor(mm, 32, 64));
        Mw[j] = __builtin_amdgcn_readfirstlane((mm + 3) >> 2);  // scalar trips 0..16
    }

    // ---- denominator: 16 static evals from LDS (ends -> exact 0 via -inf) -----
    float accD = 0.f;
#pragma unroll
    for (int m = 0; m < 16; ++m) {
        const float2 dd = s_den[m * 4 + sub];
        accD += exp2_fast(fmaf(bm1, dd.y, am1 * dd.x));
    }

    // ---- hoisted first pair: identical addresses for ALL 9 loops --------------
    const float2 P0 = s_num[sub + 1];                 // i of trip 0, slot A
    const float2 P1 = s_num[sub + 5];                 // i of trip 1, slot B

    // ---- numerators: 9 loops, exact-count pairing + prefetch double-buffer ----
    // Overshoot lanes within a live chunk are masked to exact 0 -> sums unchanged.
    float acc[9];
#pragma unroll
    for (int j = 0; j < 9; ++j) {
        const float xj  = xfj[j];
        const float axj = alxj[j];
        const int   imv = imj[j];
        const int   M   = Mw[j];                      // wave-uniform scalar
        float a0 = 0.f, a1 = 0.f;
        float2 t0 = P0, t1 = P1;                      // first pair: no LDS wait
        int m = 0;
        for (; m + 2 <= M; m += 2) {                  // pairs; prefetch next pair
            const float2 n0 = s_num[(m + 2) * 4 + sub + 1];  // issued before compute;
            const float2 n1 = s_num[(m + 3) * 4 + sub + 1];  // latency hides under body
            const int i0 = m * 4 + sub + 1;
            const int i1 = i0 + 4;
            const float w0 = fmaf(-t0.x, xj, 1.0f);
            const float w1 = fmaf(-t1.x, xj, 1.0f);
            const float e0v = fmaf(bm1, __log2f(w0), fmaf(am1, t0.y, axj));
            const float e1v = fmaf(bm1, __log2f(w1), fmaf(am1, t1.y, axj));
            const float y0 = exp2_fast(e0v);
            const float y1 = exp2_fast(e1v);
            a0 += (i0 <= imv) ? y0 : 0.f;             // i >= 1 by construction
            a1 += (i1 <= imv) ? y1 : 0.f;
            t0 = n0; t1 = n1;
        }
        if (m < M) {                                  // wave-uniform scalar tail
            const int i0 = m * 4 + sub + 1;
            const float w0 = fmaf(-t0.x, xj, 1.0f);   // t0 already resident
            const float e0v = fmaf(bm1, __log2f(w0), fmaf(am1, t0.y, axj));
            const float y0 = exp2_fast(e0v);
            a0 += (i0 <= imv) ? y0 : 0.f;
        }
        acc[j] = a0 + a1;
    }

    // ---- reduce across the 4-group --------------------------------------------
#pragma unroll
    for (int d = 1; d < 4; d <<= 1) {
        accD += __shfl_xor(accD, d, 64);
#pragma unroll
        for (int j = 0; j < 9; ++j) acc[j] += __shfl_xor(acc[j], d, 64);
    }

    // ---- epilogue: cdf -> mass; lane sub stores indices {sub, sub+4, sub+8} ---
    const float dtf = (float)(1.0 / 63.0);
    const float rB  = 1.0f / (accD * dtf);
    float cdfv[9];
#pragma unroll
    for (int j = 0; j < 9; ++j) cdfv[j] = (acc[j] * dtf) * rB;

    const float o0 = (sub == 0) ? cdfv[0]
                   : (sub == 1) ? (cdfv[1] - cdfv[0])
                   : (sub == 2) ? (cdfv[2] - cdfv[1])
                   :              (cdfv[3] - cdfv[2]);
    const float o1 = (sub == 0) ? (cdfv[4] - cdfv[3])
                   : (sub == 1) ? (cdfv[5] - cdfv[4])
                   : (sub == 2) ? (cdfv[6] - cdfv[5])
                   :              (cdfv[7] - cdfv[6]);
    const float o2 = (sub == 0) ? (cdfv[8] - cdfv[7])
                   :              (1.0f - cdfv[8]);   // sub==1; sub>=2 unused
    if (valid) {
        const long long ob = (long long)s * 10;
        out[ob + sub]     = o0;
        out[ob + 4 + sub] = o1;
        if (sub < 2) out[ob + 8 + sub] = o2;
    }
}

extern "C" void kernel_launch(void* const* d_in, const int* in_sizes, int n_in,
                              void* d_out, int out_size, void* d_ws, size_t ws_size,
                              hipStream_t stream) {
    (void)n_in; (void)out_size; (void)d_ws; (void)ws_size;
    const int*   uid = (const int*)d_in[0];
    const int*   iid = (const int*)d_in[1];
    const float* uf  = (const float*)d_in[2];
    const float* vf  = (const float*)d_in[3];
    const float* ubt = (const float*)d_in[4];
    const float* ibt = (const float*)d_in[5];
    const float* uae = (const float*)d_in[6];
    const float* ube = (const float*)d_in[7];
    const float* iae = (const float*)d_in[8];
    const float* ibe = (const float*)d_in[9];
    const float* gb  = (const float*)d_in[10];
    float* out = (float*)d_out;
    const int B = in_sizes[0];
    const int grid = (B + SPB - 1) / SPB;
    hipLaunchKernelGGL(lbd_kernel, dim3(grid), dim3(BLOCK), 0, stream,
                       uid, iid, uf, vf, ubt, ibt, uae, ube, iae, ibe, gb, out, B);
}

// Round 11
// 122.559 us; speedup vs baseline: 1.0220x; 1.0220x over previous
//
#include <hip/hip_runtime.h>
#include <math.h>

#define BLOCK 256
#define SPB (BLOCK / 4)   // 64 samples per block; 4 lanes cooperate per sample
// Session rules: (R4) no runtime-indexed register arrays; (R5) no fine-grained
// scalar guards around register-resident straight-line code; (R7) dynamic chunk
// loops with wave-uniform scalar bounds + LDS t-table; (R9) exact-count pairing
// + i=1 shift; (R10) prefetch double-buffer (profiled -20%). R11: merge adjacent
// edge pairs -> 4 trans chains in flight per trip, shared t-reads. Extra trips
// masked to exact +0.0 -> per-edge sums bit-identical.

struct F4a4 { float a, b, c, d; };   // 16B load at 4B alignment -> global_load_dwordx4

__device__ __forceinline__ float exp2_fast(float x) {
#if __has_builtin(__builtin_amdgcn_exp2f)
    return __builtin_amdgcn_exp2f(x);   // bare v_exp_f32
#else
    return __expf(x * 0.69314718055994531f);
#endif
}

// Inline f64 exp, rel err ~7e-15. Proven R5-R10 (absmax identical to libm).
__device__ __forceinline__ double exp_f64_fast(double x) {
    const double L2E = 1.4426950408889634074;
    const double LN2 = 0.69314718055994530942;
    double n = rint(x * L2E);
    double r = fma(x, L2E, -n);
    double w = r * LN2;
    double p = 2.08767569878680989792e-9;             // 1/12!
    p = fma(p, w, 2.50521083854417187751e-8);
    p = fma(p, w, 2.75573192239858906526e-7);
    p = fma(p, w, 2.75573192239858925110e-6);
    p = fma(p, w, 2.48015873015873015873e-5);
    p = fma(p, w, 1.98412698412698412698e-4);
    p = fma(p, w, 1.38888888888888888889e-3);
    p = fma(p, w, 8.33333333333333333333e-3);
    p = fma(p, w, 4.16666666666666666667e-2);
    p = fma(p, w, 1.66666666666666666667e-1);
    p = fma(p, w, 0.5);
    p = fma(p, w, 1.0);
    p = fma(p, w, 1.0);
    const double sc = __longlong_as_double((long long)(1023 + (int)n) << 52);
    return p * sc;
}

__global__ __launch_bounds__(BLOCK) void lbd_kernel(
    const int* __restrict__ uid_in, const int* __restrict__ iid_in,
    const float* __restrict__ uf,  const float* __restrict__ vf,
    const float* __restrict__ ubt, const float* __restrict__ ibt,
    const float* __restrict__ uae, const float* __restrict__ ube,
    const float* __restrict__ iae, const float* __restrict__ ibe,
    const float* __restrict__ gbp, float* __restrict__ out, int B)
{
    // Sample-independent t-grid tables: built once per block.
    // s_num padded to 72: prefetch reads up to i <= 68; pad entries are
    // (t=1, lt=0) -> finite math, masked to exact 0 if ever consumed.
    __shared__ float2 s_num[72];   // (t_i, log2 t_i); [63..71] -> (1, 0)
    __shared__ float2 s_den[64];   // (log2 t_i, log2(1-t_i))
    const int tid = threadIdx.x;
    if (tid < 72) {
        const double STEP0 = 1.0 / 63.0;
        float tf = (tid >= 63) ? 1.0f : (float)((double)tid * STEP0); // exact np linspace f32
        const float lt = __log2f(tf);                 // tid>=63 -> 0
        s_num[tid] = make_float2(tf, lt);
        if (tid < 64) s_den[tid] = make_float2(lt, __log2f(1.0f - tf));
    }
    __syncthreads();

    const int sub = tid & 3;                          // lane within 4-lane sample group
    const int s0  = blockIdx.x * SPB + (tid >> 2);
    const bool valid = (s0 < B);
    const int s = valid ? s0 : (B - 1);               // clamp: keep lanes live for shuffles

    const int u = uid_in[s];
    const int v = iid_in[s];

    // ---- feature gather: 4 x dwordx4 per table; lane covers 16c+4*sub..+3 -----
    const float* pu = uf + (long long)u * 65;
    const float* pv = vf + (long long)v * 65;
    float dotp = 0.f, sup = 0.f, svp = 0.f;
#pragma unroll
    for (int c = 0; c < 4; ++c) {
        const F4a4 a = *(const F4a4*)(pu + c * 16 + sub * 4);
        const F4a4 b = *(const F4a4*)(pv + c * 16 + sub * 4);
        dotp += a.a * b.a + a.b * b.b + a.c * b.c + a.d * b.d;
        sup  += a.a * a.a + a.b * a.b + a.c * a.c + a.d * a.d;
        svp  += b.a * b.a + b.b * b.b + b.c * b.c + b.d * b.d;
    }
#pragma unroll
    for (int d = 1; d < 4; d <<= 1) {                 // butterfly within 4-group
        dotp += __shfl_xor(dotp, d, 64);
        sup  += __shfl_xor(sup,  d, 64);
        svp  += __shfl_xor(svp,  d, 64);
    }

    // ---- embedding gather dedup: 1 load/lane + shuffles (smooth path) ---------
    float emb;
    {
        const float* ep = (sub == 0) ? (uae + u)
                        : (sub == 1) ? (iae + v)
                        : (sub == 2) ? (ube + u)
                        :              (ibe + v);
        emb = *ep;
    }
    const float ua_ = __shfl(emb, 0, 4);
    const float ia_ = __shfl(emb, 1, 4);
    const float ub_ = __shfl(emb, 2, 4);
    const float ib_ = __shfl(emb, 3, 4);

    // ---- alpha / beta (smooth; 4 lanes redundantly) ---------------------------
    const float gb = gbp[0];
    const float len_prod = sqrtf(sup) * sqrtf(svp);
    const float EPS = 1e-6f;
    const float HI  = (float)(1.0 - 1e-6);
    float mu = 0.5f + (0.5f * dotp) / fmaxf(len_prod, EPS);
    mu = fminf(fmaxf(mu, EPS), HI);
    const float ups = fmaxf(fabsf(dotp), EPS);
    const float al0 = fmaxf(0.01f, mu * ups);
    const float be0 = fmaxf(0.01f, ups - al0);
    const float alpha = fmaxf(0.01f, ((gb + al0) + ua_) + ia_);
    const float beta  = fmaxf(0.01f, ((gb + be0) + ub_) + ib_);
    const float am1 = alpha - 1.0f;                   // > 0 (gb = 2.0)
    const float bm1 = beta  - 1.0f;                   // > 0

    // ---- bin-edge chain in f64 (mask-critical; slop budget ~1e-11 rel) --------
    // Lane sub owns contiguous bins lb..lb+2 (lane3: bin 9 only).
    const double STEP = 1.0 / 63.0;
    const int lb = 3 * sub;
    double e0, e1 = 0.0, e2 = 0.0;
    {
        const long long ur = (long long)u * 10, vr = (long long)v * 10;
        const int i1 = (lb + 1 <= 9) ? lb + 1 : 9;    // clamp to stay in-bounds
        const int i2 = (lb + 2 <= 9) ? lb + 2 : 9;
        e0 = exp_f64_fast((double)ubt[ur + lb] + (double)ibt[vr + lb]);
        const double t1 = exp_f64_fast((double)ubt[ur + i1] + (double)ibt[vr + i1]);
        const double t2 = exp_f64_fast((double)ubt[ur + i2] + (double)ibt[vr + i2]);
        if (lb + 1 <= 9) e1 = t1;                     // lane3 contributes only bin 9
        if (lb + 2 <= 9) e2 = t2;
    }
    const double c0 = e0, c1 = c0 + e1, c2 = c1 + e2; // local cumsum (3 bins)
    double p = c2;                                    // local total
#pragma unroll
    for (int d = 1; d < 4; d <<= 1) {                 // inclusive scan of totals
        const double t = __shfl_up(p, d, 4);
        if (sub >= d) p += t;
    }
    const double ssum = __shfl(p, 3, 4);              // grand total (10 bins)
    const double rsum = 1.0 / ssum;                   // 1 IEEE div; <=2ulp slop ok
    const double ex   = p - c2;                       // exclusive prefix
    // own edges at static slots r=0..2 (global edge index lb+r, valid if <= 8)
    float xf_own[3] = {0.f, 0.f, 0.f}, lx_own[3] = {0.f, 0.f, 0.f};
    int   im_own[3] = {0, 0, 0};
    const double cg0 = ex + c0, cg1 = ex + c1, cg2 = ex + c2;
#pragma unroll
    for (int r = 0; r < 3; ++r) {
        const double cgr = (r == 0) ? cg0 : (r == 1) ? cg1 : cg2;
        if (lb + r <= 8) {
            const double x = cgr * rsum;              // f64 mul by reciprocal
            int k = (int)(x * 63.0);
            k = (k > 62) ? 62 : k;
            const int dec = ((double)k * STEP > x) ? 1 : 0;
            const int inc = ((k < 62) && ((double)(k + 1) * STEP <= x)) ? 1 : 0;
            im_own[r] = k + inc - dec;                // exact im, branch-free
            xf_own[r] = (float)x;
            lx_own[r] = __log2f(xf_own[r]);
        }
    }

    // ---- broadcast edges to the 4-group; wave-uniform scalar chunk bounds -----
    // With the i = 4m+sub+1 shift, trips = ceil(im/4) (exact; no dead i=0 eval).
    float xfj[9], alxj[9];
    int   imj[9], Mw[9];
#pragma unroll
    for (int j = 0; j < 9; ++j) {
        const int src  = j / 3;                       // compile-time
        const int slot = j % 3;                       // compile-time
        const float xo = (slot == 0) ? xf_own[0] : (slot == 1) ? xf_own[1] : xf_own[2];
        const float lo = (slot == 0) ? lx_own[0] : (slot == 1) ? lx_own[1] : lx_own[2];
        const int   io = (slot == 0) ? im_own[0] : (slot == 1) ? im_own[1] : im_own[2];
        xfj[j]  = __shfl(xo, src, 4);
        alxj[j] = am1 * __shfl(lo, src, 4);
        imj[j]  = __shfl(io, src, 4);
        int mm = imj[j];
        mm = max(mm, __shfl_xor(mm, 4, 64));          // max over the wave's 16 groups
        mm = max(mm, __shfl_xor(mm, 8, 64));
        mm = max(mm, __shfl_xor(mm, 16, 64));
        mm = max(mm, __shfl_xor(mm, 32, 64));
        Mw[j] = __builtin_amdgcn_readfirstlane((mm + 3) >> 2);  // scalar trips 0..16
    }

    // ---- denominator: 16 static evals from LDS (ends -> exact 0 via -inf) -----
    float accD = 0.f;
#pragma unroll
    for (int m = 0; m < 16; ++m) {
        const float2 dd = s_den[m * 4 + sub];
        accD += exp2_fast(fmaf(bm1, dd.y, am1 * dd.x));
    }

    // ---- hoisted first pair: identical addresses for ALL loops ----------------
    const float2 P0 = s_num[sub + 1];                 // i of trip 0
    const float2 P1 = s_num[sub + 5];                 // i of trip 1

    float acc[9];

    // ---- merged edge-pair loops: 4 trans chains/trip, shared t-reads ----------
    // Per-edge accumulation (even chunks -> a?0, odd -> a?1, ascending m) is
    // bit-identical to R9/R10; extra trips for the smaller edge add exact +0.0.
#define MERGED_LOOP(j1, j2)                                                        \
    {                                                                              \
        const float xA = xfj[j1], aA = alxj[j1];                                   \
        const float xB = xfj[j2], aB = alxj[j2];                                   \
        const int   iA = imj[j1], iB = imj[j2];                                    \
        const int   M  = (Mw[j1] > Mw[j2]) ? Mw[j1] : Mw[j2];  /* scalar */        \
        float aA0 = 0.f, aA1 = 0.f, aB0 = 0.f, aB1 = 0.f;                          \
        float2 t0 = P0, t1 = P1;                                                   \
        int m = 0;                                                                 \
        for (; m + 2 <= M; m += 2) {                                               \
            const float2 n0 = s_num[(m + 2) * 4 + sub + 1];                        \
            const float2 n1 = s_num[(m + 3) * 4 + sub + 1];                        \
            const int i0 = m * 4 + sub + 1;                                        \
            const int i1 = i0 + 4;                                                 \
            const float wA0 = fmaf(-t0.x, xA, 1.0f);                               \
            const float wA1 = fmaf(-t1.x, xA, 1.0f);                               \
            const float wB0 = fmaf(-t0.x, xB, 1.0f);                               \
            const float wB1 = fmaf(-t1.x, xB, 1.0f);                               \
            const float eA0 = fmaf(bm1, __log2f(wA0), fmaf(am1, t0.y, aA));        \
            const float eA1 = fmaf(bm1, __log2f(wA1), fmaf(am1, t1.y, aA));        \
            const float eB0 = fmaf(bm1, __log2f(wB0), fmaf(am1, t0.y, aB));        \
            const float eB1 = fmaf(bm1, __log2f(wB1), fmaf(am1, t1.y, aB));        \
            const float yA0 = exp2_fast(eA0), yA1 = exp2_fast(eA1);                \
            const float yB0 = exp2_fast(eB0), yB1 = exp2_fast(eB1);                \
            aA0 += (i0 <= iA) ? yA0 : 0.f;                                         \
            aA1 += (i1 <= iA) ? yA1 : 0.f;                                         \
            aB0 += (i0 <= iB) ? yB0 : 0.f;                                         \
            aB1 += (i1 <= iB) ? yB1 : 0.f;                                         \
            t0 = n0; t1 = n1;                                                      \
        }                                                                          \
        if (m < M) {                                                               \
            const int i0 = m * 4 + sub + 1;                                        \
            const float wA0 = fmaf(-t0.x, xA, 1.0f);                               \
            const float wB0 = fmaf(-t0.x, xB, 1.0f);                               \
            const float eA0 = fmaf(bm1, __log2f(wA0), fmaf(am1, t0.y, aA));        \
            const float eB0 = fmaf(bm1, __log2f(wB0), fmaf(am1, t0.y, aB));        \
            aA0 += (i0 <= iA) ? exp2_fast(eA0) : 0.f;                              \
            aB0 += (i0 <= iB) ? exp2_fast(eB0) : 0.f;                              \
        }                                                                          \
        acc[j1] = aA0 + aA1;                                                       \
        acc[j2] = aB0 + aB1;                                                       \
    }

    MERGED_LOOP(0, 1)
    MERGED_LOOP(2, 3)
    MERGED_LOOP(4, 5)
    MERGED_LOOP(6, 7)
#undef MERGED_LOOP

    // ---- solo loop for edge 8 (R10 structure: pairs + prefetch + tail) --------
    {
        const float xj  = xfj[8];
        const float axj = alxj[8];
        const int   imv = imj[8];
        const int   M   = Mw[8];
        float a0 = 0.f, a1 = 0.f;
        float2 t0 = P0, t1 = P1;
        int m = 0;
        for (; m + 2 <= M; m += 2) {
            const float2 n0 = s_num[(m + 2) * 4 + sub + 1];
            const float2 n1 = s_num[(m + 3) * 4 + sub + 1];
            const int i0 = m * 4 + sub + 1;
            const int i1 = i0 + 4;
            const float w0 = fmaf(-t0.x, xj, 1.0f);
            const float w1 = fmaf(-t1.x, xj, 1.0f);
            const float e0v = fmaf(bm1, __log2f(w0), fmaf(am1, t0.y, axj));
            const float e1v = fmaf(bm1, __log2f(w1), fmaf(am1, t1.y, axj));
            const float y0 = exp2_fast(e0v);
            const float y1 = exp2_fast(e1v);
            a0 += (i0 <= imv) ? y0 : 0.f;
            a1 += (i1 <= imv) ? y1 : 0.f;
            t0 = n0; t1 = n1;
        }
        if (m < M) {
            const int i0 = m * 4 + sub + 1;
            const float w0 = fmaf(-t0.x, xj, 1.0f);
            const float e0v = fmaf(bm1, __log2f(w0), fmaf(am1, t0.y, axj));
            a0 += (i0 <= imv) ? exp2_fast(e0v) : 0.f;
        }
        acc[8] = a0 + a1;
    }

    // ---- reduce across the 4-group --------------------------------------------
#pragma unroll
    for (int d = 1; d < 4; d <<= 1) {
        accD += __shfl_xor(accD, d, 64);
#pragma unroll
        for (int j = 0; j < 9; ++j) acc[j] += __shfl_xor(acc[j], d, 64);
    }

    // ---- epilogue: cdf -> mass; lane sub stores indices {sub, sub+4, sub+8} ---
    const float dtf = (float)(1.0 / 63.0);
    const float rB  = 1.0f / (accD * dtf);
    float cdfv[9];
#pragma unroll
    for (int j = 0; j < 9; ++j) cdfv[j] = (acc[j] * dtf) * rB;

    const float o0 = (sub == 0) ? cdfv[0]
                   : (sub == 1) ? (cdfv[1] - cdfv[0])
                   : (sub == 2) ? (cdfv[2] - cdfv[1])
                   :              (cdfv[3] - cdfv[2]);
    const float o1 = (sub == 0) ? (cdfv[4] - cdfv[3])
                   : (sub == 1) ? (cdfv[5] - cdfv[4])
                   : (sub == 2) ? (cdfv[6] - cdfv[5])
                   :              (cdfv[7] - cdfv[6]);
    const float o2 = (sub == 0) ? (cdfv[8] - cdfv[7])
                   :              (1.0f - cdfv[8]);   // sub==1; sub>=2 unused
    if (valid) {
        const long long ob = (long long)s * 10;
        out[ob + sub]     = o0;
        out[ob + 4 + sub] = o1;
        if (sub < 2) out[ob + 8 + sub] = o2;
    }
}

extern "C" void kernel_launch(void* const* d_in, const int* in_sizes, int n_in,
                              void* d_out, int out_size, void* d_ws, size_t ws_size,
                              hipStream_t stream) {
    (void)n_in; (void)out_size; (void)d_ws; (void)ws_size;
    const int*   uid = (const int*)d_in[0];
    const int*   iid = (const int*)d_in[1];
    const float* uf  = (const float*)d_in[2];
    const float* vf  = (const float*)d_in[3];
    const float* ubt = (const float*)d_in[4];
    const float* ibt = (const float*)d_in[5];
    const float* uae = (const float*)d_in[6];
    const float* ube = (const float*)d_in[7];
    const float* iae = (const float*)d_in[8];
    const float* ibe = (const float*)d_in[9];
    const float* gb  = (const float*)d_in[10];
    float* out = (float*)d_out;
    const int B = in_sizes[0];
    const int grid = (B + SPB - 1) / SPB;
    hipLaunchKernelGGL(lbd_kernel, dim3(grid), dim3(BLOCK), 0, stream,
                       uid, iid, uf, vf, ubt, ibt, uae, ube, iae, ibe, gb, out, B);
}